// Round 1
// baseline (326.329 us; speedup 1.0000x reference)
//
#include <hip/hip_runtime.h>

#define BATCH 4096
#define TT 512
#define HH 64
#define BT 16      // batch rows per block (one MFMA M-tile)
#define XS 516     // x_s row stride in floats (bank-spread, 16B-aligned rows)
#define HS 72      // h buffer row stride in bf16 (+8 pad: spreads A-frag banks, keeps 16B align)

typedef __attribute__((ext_vector_type(8))) short short8;
typedef __attribute__((ext_vector_type(4))) float floatx4;

__device__ __forceinline__ float sigf(float x) {
    // 1/(1+2^(-x*log2e)) ; exp2+rcp are the cheap saturating path (quarter-rate pipe)
    return __builtin_amdgcn_rcpf(1.f + __builtin_amdgcn_exp2f(-1.44269504089f * x));
}
__device__ __forceinline__ float tanhf_(float x) {
    float e = __builtin_amdgcn_exp2f(2.88539008178f * x);   // 2^(2x*log2e) = e^(2x)
    return 1.f - 2.f * __builtin_amdgcn_rcpf(e + 1.f);
}
__device__ __forceinline__ unsigned short f2bf(float f) {   // RNE f32->bf16
    unsigned u = __float_as_uint(f);
    u = u + 0x7FFFu + ((u >> 16) & 1u);
    return (unsigned short)(u >> 16);
}

__global__ __launch_bounds__(256) void lstm_kernel(
    const float* __restrict__ x, const float* __restrict__ W_ih,
    const float* __restrict__ W_hh, const float* __restrict__ b_ih,
    const float* __restrict__ b_hh, const float* __restrict__ W_out,
    const float* __restrict__ b_out, float* __restrict__ out)
{
    __shared__ __align__(16) float x_s[BT * XS];
    __shared__ __align__(16) unsigned short hb[2][BT * HS];  // bf16 h, double-buffered
    __shared__ __align__(16) float hf[BT * 65];              // final h in fp32 for the head

    const int tid = threadIdx.x;
    const int w = tid >> 6;       // wave id 0..3  -> owns gate col-tiles {w, w+4, w+8, w+12}
    const int l = tid & 63;
    const int q = l >> 4;         // quad-of-16 within wave
    const int c = l & 15;
    const int n = 16 * w + c;     // hidden index this lane owns for activations
    const int bbase = blockIdx.x * BT;

    // ---- stage x[bbase..bbase+15][0..511] into LDS, coalesced float4 ----
    for (int i = 0; i < 8; ++i) {
        int flat = i * 256 + tid;              // 2048 float4s
        int row = flat >> 7, c4 = flat & 127;
        const float4* xg = reinterpret_cast<const float4*>(x + (size_t)(bbase + row) * TT);
        float4 v = xg[c4];
        *reinterpret_cast<float4*>(&x_s[row * XS + c4 * 4]) = v;
    }
    for (int i = tid; i < BT * HS; i += 256) hb[0][i] = 0;   // h0 = 0

    // ---- persistent B-fragments: W_hh rows for gates g = 64*t + n, bf16, in VGPRs ----
    // B-frag layout (16x16x32): lane holds B[k=(l>>4)*8+j][ncol=l&15]; B[k][g]=W_hh[g][k]
    short8 bfr[4][2];
    float wih[4], bb[4];
    for (int t = 0; t < 4; ++t) {
        int g = 64 * t + n;
        wih[t] = W_ih[g];
        bb[t] = b_ih[g] + b_hh[g];
        for (int ks = 0; ks < 2; ++ks) {
            const float* wp = W_hh + g * 64 + ks * 32 + q * 8;
            short8 v;
            #pragma unroll
            for (int j = 0; j < 8; ++j) v[j] = (short)f2bf(wp[j]);
            bfr[t][ks] = v;
        }
    }
    float cst[4] = {0.f, 0.f, 0.f, 0.f};   // c-state for batch rows 4q+r, hidden n

    __syncthreads();

    int cur = 0;
    for (int ts = 0; ts < TT; ++ts) {
        // A-fragments: A[m=l&15][k=(l>>4)*8+j (+32)] = h[batch row c][hidden k]
        const unsigned short* hc = hb[cur];
        short8 a0 = *reinterpret_cast<const short8*>(hc + c * HS + q * 8);
        short8 a1 = *reinterpret_cast<const short8*>(hc + c * HS + q * 8 + 32);

        float xr[4];
        #pragma unroll
        for (int r = 0; r < 4; ++r) xr[r] = x_s[(q * 4 + r) * XS + ts];

        // C init = x_proj = x*W_ih[g] + (b_ih+b_hh)[g]; C/D: row=4q+r, col=c
        floatx4 acc[4];
        #pragma unroll
        for (int t = 0; t < 4; ++t)
            #pragma unroll
            for (int r = 0; r < 4; ++r)
                acc[t][r] = fmaf(xr[r], wih[t], bb[t]);

        #pragma unroll
        for (int t = 0; t < 4; ++t) {
            acc[t] = __builtin_amdgcn_mfma_f32_16x16x32_bf16(a0, bfr[t][0], acc[t], 0, 0, 0);
            acc[t] = __builtin_amdgcn_mfma_f32_16x16x32_bf16(a1, bfr[t][1], acc[t], 0, 0, 0);
        }

        // activations: lane owns (rows 4q+r, hidden n); tiles t = i,f,g,o
        unsigned short* hnx = hb[cur ^ 1];
        #pragma unroll
        for (int r = 0; r < 4; ++r) {
            float ig = sigf(acc[0][r]);
            float fg = sigf(acc[1][r]);
            float gg = tanhf_(acc[2][r]);
            float og = sigf(acc[3][r]);
            float cv = fmaf(fg, cst[r], ig * gg);
            cst[r] = cv;
            float hv = og * tanhf_(cv);
            hnx[(q * 4 + r) * HS + n] = f2bf(hv);
            if (ts == TT - 1) hf[(q * 4 + r) * 65 + n] = hv;   // fp32 h for the head
        }
        cur ^= 1;
        __syncthreads();
    }

    // ---- head: out[b][o] = sum_n hf[b][n]*W_out[o][n] + b_out[o] ----
    if (tid < BT * 3) {
        int row = tid / 3, o = tid % 3;
        float s = b_out[o];
        #pragma unroll 8
        for (int k = 0; k < HH; ++k) s = fmaf(hf[row * 65 + k], W_out[o * 64 + k], s);
        out[(size_t)(bbase + row) * 3 + o] = s;
    }
}

extern "C" void kernel_launch(void* const* d_in, const int* in_sizes, int n_in,
                              void* d_out, int out_size, void* d_ws, size_t ws_size,
                              hipStream_t stream) {
    const float* x     = (const float*)d_in[0];
    const float* W_ih  = (const float*)d_in[1];
    const float* W_hh  = (const float*)d_in[2];
    const float* b_ih  = (const float*)d_in[3];
    const float* b_hh  = (const float*)d_in[4];
    const float* W_out = (const float*)d_in[5];
    const float* b_out = (const float*)d_in[6];
    float* out = (float*)d_out;
    hipLaunchKernelGGL(lstm_kernel, dim3(BATCH / BT), dim3(256), 0, stream,
                       x, W_ih, W_hh, b_ih, b_hh, W_out, b_out, out);
}